// Round 4
// baseline (67.591 us; speedup 1.0000x reference)
//
#include <hip/hip_runtime.h>
#include <math.h>

#define BB 2
#define NN 512
#define DD 32
#define HH 64
#define JT 2
#define IPB 2
#define NBLK1 (BB*(NN/IPB)*JT)   // 1024
#define NBLK3 (BB*64*JT)         // 256

// ws layout (float offsets)
#define SC_OFF  0                        // scores: B*N*N = 524288
#define MF_OFF  (SC_OFF + BB*NN*NN)      // 0.5*M B-frags: 4096 halves = 2048 fl
#define WF_OFF  (MF_OFF + 2048)          // 0.25*Ws1 B-frags: 2048 halves = 1024 fl
#define W1F_OFF (WF_OFF + 1024)          // W1/b1 A-table: 192 halves (pad 128 fl)
#define PM2_OFF (W1F_OFF + 128)          // per-pass1-block max: 1024
#define PS2_OFF (PM2_OFF + NBLK1)        // per-pass1-block sumexp: 1024
#define A_OFF   (PS2_OFF + NBLK1)        // A accumulator: B*64 = 128
#define CS_OFF  (A_OFF + BB*HH)          // col sums: B*N = 1024
#define TK_OFF  (CS_OFF + BB*NN)         // ticket (int, 1 slot)

typedef _Float16 half8 __attribute__((ext_vector_type(8)));
typedef float    f32x4 __attribute__((ext_vector_type(4)));

__device__ __forceinline__ half8 h8splat(float v) {
    _Float16 h = (_Float16)v;
    half8 r = {h,h,h,h,h,h,h,h};
    return r;
}

__device__ __forceinline__ void invar2(float pix, float piy, float piz,
                                       float pjx, float pjy, float pjz,
                                       float& s, float& cr) {
    s = pix*pjx + piy*pjy + piz*pjz;
    float e12 = pjx*piy - pjy*pix;
    float e13 = pjx*piz - pjz*pix;
    float e23 = pjy*piz - pjz*piy;
    cr = sqrtf(e12*e12 + e13*e13 + e23*e23);
}

// ---------------- prep-lite: fragment tables + zero accumulators ----------------
#define R2 4096                       // M frag halves
#define R3 2048                       // Ws1 frag halves
#define R4 192                        // W1/b1 table halves
#define RZ (BB*HH + BB*NN + 1)        // zeros: A, CS, ticket
#define PREP_T (R2+R3+R4+RZ)

__global__ __launch_bounds__(256) void prep(const float* __restrict__ W1,
                                            const float* __restrict__ b1,
                                            const float* __restrict__ W2,
                                            const float* __restrict__ Ws1,
                                            float* __restrict__ ws) {
    int idx = blockIdx.x * 256 + threadIdx.x;
    if (idx < R2) {
        // 0.5*(W2@Ws1) fragment: f=cf*2+kh; lane holds k=kh*32+8*(lane>>4)+t, col=cf*16+(lane&15)
        int e = idx;
        int t = e & 7, lane = (e >> 3) & 63, f = e >> 9;
        int cf = f >> 1, kh = f & 1;
        int k   = kh*32 + 8*(lane >> 4) + t;
        int col = cf*16 + (lane & 15);
        float acc = 0.f;
        #pragma unroll
        for (int d = 0; d < DD; d++) acc += W2[k*DD + d] * Ws1[d*HH + col];
        ((_Float16*)(ws + MF_OFF))[e] = (_Float16)(0.5f * acc);
    } else if (idx < R2+R3) {
        // 0.25*Ws1 fragment (K=32, k=d)
        int e = idx - R2;
        int t = e & 7, lane = (e >> 3) & 63, cf = e >> 9;
        int k   = 8*(lane >> 4) + t;
        int col = cf*16 + (lane & 15);
        ((_Float16*)(ws + WF_OFF))[e] = (_Float16)(0.25f * Ws1[k*HH + col]);
    } else if (idx < R2+R3+R4) {
        // W1/b1 table: e = ((arr*2+kh)*4+g)*8+t, k = kh*32+8g+t
        int e = idx - R2 - R3;
        int t = e & 7, rest = e >> 3;
        int g = rest & 3, kh = (rest >> 2) & 1, arr = rest >> 3;
        int k = kh*32 + 8*g + t;
        float v = (arr == 0) ? W1[k] : (arr == 1) ? W1[HH + k] : b1[k];
        ((_Float16*)(ws + W1F_OFF))[e] = (_Float16)v;
    } else if (idx < PREP_T) {
        int local = idx - (R2+R3+R4);
        if (local < BB*HH)            ws[A_OFF + local] = 0.f;
        else if (local < BB*HH+BB*NN) ws[CS_OFF + (local - BB*HH)] = 0.f;
        else                          *(int*)(ws + TK_OFF) = 0;
    }
}

// ---------------- pass1: scores via K=96 MFMA + fused softmax partials ----------------
// block = (b, i-pair, jt). 4 waves; wave w owns j in [jt*256+w*64, +64), 2 i rows each.
__global__ __launch_bounds__(256) void pass1(const float* __restrict__ pos,
                                             const float* __restrict__ values,
                                             const float* __restrict__ b2,
                                             const float* __restrict__ Ws1,
                                             const float* __restrict__ bs1,
                                             const float* __restrict__ Ws2,
                                             const float* __restrict__ bs2,
                                             float* __restrict__ ws) {
    __shared__ float uqc[IPB][HH];   // (0.25*v_i + 0.5*b2)@Ws1 + bs1
    __shared__ float ws2l[HH];
    __shared__ float sm4[4], ss4[4];
    int blk = blockIdx.x;
    int jt = blk & 1;
    int ip = (blk >> 1) & 255;
    int b  = blk >> 9;
    int i0 = ip * IPB;
    int tid = threadIdx.x;
    int w    = tid >> 6;
    int lane = tid & 63;
    int g    = lane >> 4;
    int lr   = lane & 15;

    if (tid < IPB*HH) {
        int ii = tid >> 6, l = tid & 63;
        const float* vrow = values + (size_t)(b*NN + i0 + ii)*DD;
        float acc = bs1[l];
        #pragma unroll
        for (int d = 0; d < DD; d++) acc += (0.25f*vrow[d] + 0.5f*b2[d]) * Ws1[d*HH + l];
        uqc[ii][l] = acc;
        if (ii == 0) ws2l[l] = Ws2[l];
    }

    // B fragments from ws (coalesced 16B/lane, L2-hit)
    const half8* mf8 = (const half8*)(ws + MF_OFF);
    const half8* wf8 = (const half8*)(ws + WF_OFF);
    half8 Bf[4][2], Wf[4];
    #pragma unroll
    for (int cf = 0; cf < 4; cf++) {
        Bf[cf][0] = mf8[(cf*2 + 0)*64 + lane];
        Bf[cf][1] = mf8[(cf*2 + 1)*64 + lane];
        Wf[cf]    = wf8[cf*64 + lane];
    }
    const half8* w1f8 = (const half8*)(ws + W1F_OFF);
    half8 W1a[2], W1b[2], B1f[2];
    #pragma unroll
    for (int kh = 0; kh < 2; kh++) {
        W1a[kh] = w1f8[(0*2 + kh)*4 + g];
        W1b[kh] = w1f8[(1*2 + kh)*4 + g];
        B1f[kh] = w1f8[(2*2 + kh)*4 + g];
    }

    float pix[IPB], piy[IPB], piz[IPB];
    #pragma unroll
    for (int ii = 0; ii < IPB; ii++) {
        pix[ii] = pos[(b*NN+i0+ii)*3+0];
        piy[ii] = pos[(b*NN+i0+ii)*3+1];
        piz[ii] = pos[(b*NN+i0+ii)*3+2];
    }
    float bs2v = bs2[0];
    half8 z8 = h8splat(0.f);

    __syncthreads();

    float m_run = -INFINITY, s_run = 0.f;

    #pragma unroll
    for (int rf = 0; rf < 4; rf++) {
        int j_a = jt*256 + w*64 + rf*16 + lr;
        float pjx = pos[(b*NN+j_a)*3+0], pjy = pos[(b*NN+j_a)*3+1], pjz = pos[(b*NN+j_a)*3+2];
        // A2 = f16(values[j_a][8g..8g+8])
        const float* vj = values + (size_t)(b*NN + j_a)*DD + 8*g;
        half8 A2;
        #pragma unroll
        for (int t = 0; t < 8; t++) A2[t] = (_Float16)vj[t];

        #pragma unroll
        for (int ii = 0; ii < IPB; ii++) {
            float s, cr;
            invar2(pix[ii],piy[ii],piz[ii],pjx,pjy,pjz,s,cr);
            half8 s8 = h8splat(s), c8 = h8splat(cr);
            half8 A0 = __builtin_elementwise_max(W1a[0]*s8 + W1b[0]*c8 + B1f[0], z8);
            half8 A1 = __builtin_elementwise_max(W1a[1]*s8 + W1b[1]*c8 + B1f[1], z8);

            f32x4 c[4];
            #pragma unroll
            for (int cf = 0; cf < 4; cf++) {
                f32x4 z = {0.f, 0.f, 0.f, 0.f};
                z = __builtin_amdgcn_mfma_f32_16x16x32_f16(A0, Bf[cf][0], z, 0, 0, 0);
                z = __builtin_amdgcn_mfma_f32_16x16x32_f16(A1, Bf[cf][1], z, 0, 0, 0);
                c[cf] = __builtin_amdgcn_mfma_f32_16x16x32_f16(A2, Wf[cf], z, 0, 0, 0);
            }

            float part0 = 0.f, part1 = 0.f, part2 = 0.f, part3 = 0.f;
            #pragma unroll
            for (int cf = 0; cf < 4; cf++) {
                int lc = cf*16 + lr;
                float base = uqc[ii][lc];
                float w2v  = ws2l[lc];
                part0 += fmaxf(c[cf][0] + base, 0.f) * w2v;
                part1 += fmaxf(c[cf][1] + base, 0.f) * w2v;
                part2 += fmaxf(c[cf][2] + base, 0.f) * w2v;
                part3 += fmaxf(c[cf][3] + base, 0.f) * w2v;
            }
            #pragma unroll
            for (int m = 1; m < 16; m <<= 1) {
                part0 += __shfl_xor(part0, m);
                part1 += __shfl_xor(part1, m);
                part2 += __shfl_xor(part2, m);
                part3 += __shfl_xor(part3, m);
            }
            float x0 = part0 + bs2v, x1 = part1 + bs2v, x2 = part2 + bs2v, x3 = part3 + bs2v;
            if (lr == 0) {
                float4 outv; outv.x = x0; outv.y = x1; outv.z = x2; outv.w = x3;
                *(float4*)(ws + SC_OFF + (size_t)(b*NN + i0 + ii)*NN + jt*256 + w*64 + rf*16 + 4*g) = outv;
            }
            float mm = fmaxf(fmaxf(x0, x1), fmaxf(x2, x3));
            float nm = fmaxf(m_run, mm);
            s_run = s_run*__expf(m_run - nm)
                  + __expf(x0 - nm) + __expf(x1 - nm) + __expf(x2 - nm) + __expf(x3 - nm);
            m_run = nm;
        }
    }

    #pragma unroll
    for (int off = 16; off < 64; off <<= 1) {
        float om = __shfl_xor(m_run, off);
        float os = __shfl_xor(s_run, off);
        float nm = fmaxf(m_run, om);
        s_run = s_run*__expf(m_run - nm) + os*__expf(om - nm);
        m_run = nm;
    }
    if (lane == 0) { sm4[w] = m_run; ss4[w] = s_run; }
    __syncthreads();
    if (tid == 0) {
        float M0 = sm4[0], S0 = ss4[0];
        #pragma unroll
        for (int q = 1; q < 4; q++) {
            float nm = fmaxf(M0, sm4[q]);
            S0 = S0*__expf(M0 - nm) + ss4[q]*__expf(sm4[q] - nm);
            M0 = nm;
        }
        ws[PM2_OFF + blk] = M0;
        ws[PS2_OFF + blk] = S0;
    }
}

// ---------------- pass3: reduce partials + accumulate A/cs + fused final ----------------
__global__ __launch_bounds__(256) void pass3(const float* __restrict__ pos,
                                             const float* __restrict__ values,
                                             const float* __restrict__ W1,
                                             const float* __restrict__ b1,
                                             const float* __restrict__ W2,
                                             const float* __restrict__ b2,
                                             float* __restrict__ ws,
                                             float* __restrict__ out) {
    __shared__ float w1a[HH], w1b[HH], b1l[HH];
    __shared__ float Aw[4*HH];
    __shared__ float red[8];
    __shared__ float MS[2];
    __shared__ float fin[4*HH];
    __shared__ int lastf;
    int blk = blockIdx.x;             // 256 = B * 64ic * JT
    int jt = blk & 1;
    int ic = (blk >> 1) & 63;
    int b  = blk >> 7;
    int tid = threadIdx.x;
    int w = tid >> 6, lane = tid & 63;

    // ---- redundant per-block reduction of this batch's 512 (m,s) partials ----
    {
        float m = -INFINITY, s = 0.f;
        #pragma unroll
        for (int q = 0; q < 2; q++) {
            int p = b*512 + tid + q*256;
            float pm = ws[PM2_OFF + p], ps = ws[PS2_OFF + p];
            float nm = fmaxf(m, pm);
            s = s*__expf(m - nm) + ps*__expf(pm - nm);
            m = nm;
        }
        for (int off = 1; off < 64; off <<= 1) {
            float om = __shfl_xor(m, off);
            float os = __shfl_xor(s, off);
            float nm = fmaxf(m, om);
            s = s*__expf(m - nm) + os*__expf(om - nm);
            m = nm;
        }
        if (lane == 0) { red[w*2] = m; red[w*2+1] = s; }
    }
    if (tid < HH) { w1a[tid] = W1[tid]; w1b[tid] = W1[HH+tid]; b1l[tid] = b1[tid]; }
    __syncthreads();
    if (tid == 0) {
        float M0 = red[0], S0 = red[1];
        #pragma unroll
        for (int q = 1; q < 4; q++) {
            float nm = fmaxf(M0, red[q*2]);
            S0 = S0*__expf(M0 - nm) + red[q*2+1]*__expf(red[q*2] - nm);
            M0 = nm;
        }
        MS[0] = M0; MS[1] = 1.f / S0;
    }
    __syncthreads();
    float maxv = MS[0], inv = MS[1];

    int j = jt*256 + tid;
    float pjx = pos[(b*NN+j)*3+0], pjy = pos[(b*NN+j)*3+1], pjz = pos[(b*NN+j)*3+2];
    float A[HH];
    #pragma unroll
    for (int k = 0; k < HH; k++) A[k] = 0.f;
    float cs = 0.f;

    for (int ii = 0; ii < 8; ii++) {
        int i = ic*8 + ii;
        float pix = pos[(b*NN+i)*3+0], piy = pos[(b*NN+i)*3+1], piz = pos[(b*NN+i)*3+2];
        float s, cr;
        invar2(pix,piy,piz,pjx,pjy,pjz,s,cr);
        float wgt = __expf(ws[SC_OFF + (size_t)(b*NN+i)*NN + j] - maxv) * inv;
        cs += wgt;
        #pragma unroll
        for (int k = 0; k < HH; k++) {
            float h = fmaxf(w1a[k]*s + w1b[k]*cr + b1l[k], 0.f);
            A[k] += wgt*h;
        }
    }
    atomicAdd(&ws[CS_OFF + b*NN + j], cs);

    #pragma unroll
    for (int k = 0; k < HH; k++) {
        for (int off = 1; off < 64; off <<= 1) A[k] += __shfl_xor(A[k], off);
    }
    if (lane == 0) {
        #pragma unroll
        for (int k = 0; k < HH; k++) Aw[w*HH + k] = A[k];
    }
    __syncthreads();
    if (tid < HH) {
        float v = Aw[tid] + Aw[HH+tid] + Aw[2*HH+tid] + Aw[3*HH+tid];
        atomicAdd(&ws[A_OFF + b*HH + tid], v);
    }

    // ---- last-block fused final ----
    __threadfence();
    __syncthreads();
    if (tid == 0) {
        int old = atomicAdd((int*)(ws + TK_OFF), 1);
        lastf = (old == NBLK3 - 1);
    }
    __syncthreads();
    if (lastf) {
        __threadfence();
        int o = tid & 63, q = tid >> 6;
        int bo = o >> 5, d = o & 31;
        float part = 0.f;
        for (int n = q*128; n < q*128 + 128; n++)
            part += ws[CS_OFF + bo*NN + n] * values[(size_t)(bo*NN + n)*DD + d];
        fin[q*64 + o] = part;
        __syncthreads();
        if (tid < 64) {
            float vsum = fin[o] + fin[64+o] + fin[128+o] + fin[192+o];
            float aw = 0.f;
            #pragma unroll
            for (int k = 0; k < HH; k++) aw += ws[A_OFF + bo*HH + k] * W2[k*DD + d];
            out[o] = 0.5f*b2[d] + 0.5f*aw + 0.5f*vsum;
        }
    }
}

extern "C" void kernel_launch(void* const* d_in, const int* in_sizes, int n_in,
                              void* d_out, int out_size, void* d_ws, size_t ws_size,
                              hipStream_t stream) {
    (void)in_sizes; (void)n_in; (void)out_size; (void)ws_size;
    const float* pos    = (const float*)d_in[0];
    const float* values = (const float*)d_in[1];
    const float* W1     = (const float*)d_in[2];
    const float* b1     = (const float*)d_in[3];
    const float* W2     = (const float*)d_in[4];
    const float* b2     = (const float*)d_in[5];
    const float* Ws1    = (const float*)d_in[6];
    const float* bs1    = (const float*)d_in[7];
    const float* Ws2    = (const float*)d_in[8];
    const float* bs2    = (const float*)d_in[9];
    float* ws  = (float*)d_ws;
    float* out = (float*)d_out;

    prep  <<<(PREP_T + 255)/256, 256, 0, stream>>>(W1, b1, W2, Ws1, ws);
    pass1 <<<NBLK1, 256, 0, stream>>>(pos, values, b2, Ws1, bs1, Ws2, bs2, ws);
    pass3 <<<NBLK3, 256, 0, stream>>>(pos, values, W1, b1, W2, b2, ws, out);
}